// Round 1
// baseline (1405.965 us; speedup 1.0000x reference)
//
#include <hip/hip_runtime.h>
#include <math.h>

// tanh(x) = (e^{2x}-1)/(e^{2x}+1) = 1 - 2/(e^{2x}+1); e^{2x} = exp2(x * 2*log2(e))
// Saturates correctly: x->+inf => exp2=inf => rcp=0 => +1 ; x->-inf => exp2=0 => rcp(1)=1 => -1
__device__ __forceinline__ float fast_tanh(float x) {
    float t = __builtin_amdgcn_exp2f(x * 2.8853900817779268f);
    return fmaf(-2.0f, __builtin_amdgcn_rcpf(t + 1.0f), 1.0f);
}

// ---------------- Projection: 6 -> 100 (relu) -> 100 (relu) -> 3 ----------------
// One thread per sample. h1[100] kept in registers (loops fully unrolled).
// Layer-2 and layer-3 fused: h2[j] is consumed immediately into y0[0..2].
// All weight accesses are wave-uniform -> compiler scalarizes to s_load.
__global__ __launch_bounds__(256)
void proj_kernel(const float* __restrict__ sa,
                 const float* __restrict__ pW1, const float* __restrict__ pb1,
                 const float* __restrict__ pW2, const float* __restrict__ pb2,
                 const float* __restrict__ pW3, const float* __restrict__ pb3,
                 float* __restrict__ out, int B)
{
    const int b = blockIdx.x * 256 + threadIdx.x;
    if (b >= B) return;

    const float2* sa2 = (const float2*)sa + (size_t)b * 3;
    float2 p0 = sa2[0], p1 = sa2[1], p2 = sa2[2];
    float x[6] = {p0.x, p0.y, p1.x, p1.y, p2.x, p2.y};

    // Layer 1: h1[i] = relu(sum_k x[k] * pW1[k][i] + pb1[i])
    float h1[100];
#pragma unroll
    for (int i0 = 0; i0 < 100; i0 += 4) {
        float4 acc = *(const float4*)(pb1 + i0);
#pragma unroll
        for (int k = 0; k < 6; ++k) {
            float4 w = *(const float4*)(pW1 + k * 100 + i0);  // 400B row stride: 16B-aligned
            acc.x = fmaf(x[k], w.x, acc.x);
            acc.y = fmaf(x[k], w.y, acc.y);
            acc.z = fmaf(x[k], w.z, acc.z);
            acc.w = fmaf(x[k], w.w, acc.w);
        }
        h1[i0 + 0] = fmaxf(acc.x, 0.0f);
        h1[i0 + 1] = fmaxf(acc.y, 0.0f);
        h1[i0 + 2] = fmaxf(acc.z, 0.0f);
        h1[i0 + 3] = fmaxf(acc.w, 0.0f);
    }

    // Layer 2 (100->100, relu) fused into layer 3 (100->3)
    float y0 = pb3[0], y1 = pb3[1], y2 = pb3[2];
    for (int j0 = 0; j0 < 100; j0 += 4) {   // rolled: 25 iterations
        float4 acc = *(const float4*)(pb2 + j0);
#pragma unroll
        for (int i = 0; i < 100; ++i) {     // unrolled so h1[] stays in registers
            float4 w = *(const float4*)(pW2 + i * 100 + j0);
            float h = h1[i];
            acc.x = fmaf(h, w.x, acc.x);
            acc.y = fmaf(h, w.y, acc.y);
            acc.z = fmaf(h, w.z, acc.z);
            acc.w = fmaf(h, w.w, acc.w);
        }
        float h2a = fmaxf(acc.x, 0.0f);
        float h2b = fmaxf(acc.y, 0.0f);
        float h2c = fmaxf(acc.z, 0.0f);
        float h2d = fmaxf(acc.w, 0.0f);
        // pW3 rows j0..j0+3 are 12 contiguous floats, 48B-aligned (j0 % 4 == 0)
        float4 u0 = *(const float4*)(pW3 + j0 * 3 + 0);
        float4 u1 = *(const float4*)(pW3 + j0 * 3 + 4);
        float4 u2 = *(const float4*)(pW3 + j0 * 3 + 8);
        y0 = fmaf(h2a, u0.x, y0); y1 = fmaf(h2a, u0.y, y1); y2 = fmaf(h2a, u0.z, y2);
        y0 = fmaf(h2b, u0.w, y0); y1 = fmaf(h2b, u1.x, y1); y2 = fmaf(h2b, u1.y, y2);
        y0 = fmaf(h2c, u1.z, y0); y1 = fmaf(h2c, u1.w, y1); y2 = fmaf(h2c, u2.x, y2);
        y0 = fmaf(h2d, u2.y, y0); y1 = fmaf(h2d, u2.z, y1); y2 = fmaf(h2d, u2.w, y2);
    }
    float* o = out + (size_t)b * 3;   // out[0] slice == y0 trajectory entry
    o[0] = y0; o[1] = y1; o[2] = y2;
}

// ---------------- ODE: 15 RK4 steps of f(y) = tanh(y@oW1 + ob1) @ oW2 + ob2 ----------------
__global__ __launch_bounds__(256)
void ode_kernel(const float* __restrict__ T,
                const float* __restrict__ oW1, const float* __restrict__ ob1,
                const float* __restrict__ oW2, const float* __restrict__ ob2,
                float* __restrict__ out, int B)
{
    const int b = blockIdx.x * 256 + threadIdx.x;
    if (b >= B) return;

    const float* o0 = out + (size_t)b * 3;
    float y0 = o0[0], y1 = o0[1], y2 = o0[2];
    const float c0 = ob2[0], c1 = ob2[1], c2 = ob2[2];

    auto feval = [&](float a0, float a1, float a2, float& r0, float& r1, float& r2) {
        float s0 = c0, s1 = c1, s2 = c2;
        for (int j0 = 0; j0 < 100; j0 += 4) {   // 25 iterations, 4 independent tanh chains each
            float4 z  = *(const float4*)(ob1 + j0);
            float4 wa = *(const float4*)(oW1 + 0   + j0);
            float4 wb = *(const float4*)(oW1 + 100 + j0);
            float4 wc = *(const float4*)(oW1 + 200 + j0);
            z.x = fmaf(a0, wa.x, fmaf(a1, wb.x, fmaf(a2, wc.x, z.x)));
            z.y = fmaf(a0, wa.y, fmaf(a1, wb.y, fmaf(a2, wc.y, z.y)));
            z.z = fmaf(a0, wa.z, fmaf(a1, wb.z, fmaf(a2, wc.z, z.z)));
            z.w = fmaf(a0, wa.w, fmaf(a1, wb.w, fmaf(a2, wc.w, z.w)));
            float t0 = fast_tanh(z.x);
            float t1 = fast_tanh(z.y);
            float t2 = fast_tanh(z.z);
            float t3 = fast_tanh(z.w);
            // oW2 rows j0..j0+3: 12 contiguous floats, 48B-aligned
            float4 u0 = *(const float4*)(oW2 + j0 * 3 + 0);
            float4 u1 = *(const float4*)(oW2 + j0 * 3 + 4);
            float4 u2 = *(const float4*)(oW2 + j0 * 3 + 8);
            s0 = fmaf(t0, u0.x, s0); s1 = fmaf(t0, u0.y, s1); s2 = fmaf(t0, u0.z, s2);
            s0 = fmaf(t1, u0.w, s0); s1 = fmaf(t1, u1.x, s1); s2 = fmaf(t1, u1.y, s2);
            s0 = fmaf(t2, u1.z, s0); s1 = fmaf(t2, u1.w, s1); s2 = fmaf(t2, u2.x, s2);
            s0 = fmaf(t3, u2.y, s0); s1 = fmaf(t3, u2.z, s1); s2 = fmaf(t3, u2.w, s2);
        }
        r0 = s0; r1 = s1; r2 = s2;
    };

#pragma unroll 1
    for (int s = 0; s < 15; ++s) {
        float dt  = T[s + 1] - T[s];
        float hdt = 0.5f * dt;
        float k10, k11, k12, k20, k21, k22, k30, k31, k32, k40, k41, k42;
        feval(y0, y1, y2, k10, k11, k12);
        feval(fmaf(hdt, k10, y0), fmaf(hdt, k11, y1), fmaf(hdt, k12, y2), k20, k21, k22);
        feval(fmaf(hdt, k20, y0), fmaf(hdt, k21, y1), fmaf(hdt, k22, y2), k30, k31, k32);
        feval(fmaf(dt,  k30, y0), fmaf(dt,  k31, y1), fmaf(dt,  k32, y2), k40, k41, k42);
        float w6 = dt * (1.0f / 6.0f);
        y0 += w6 * (k10 + 2.0f * (k20 + k30) + k40);
        y1 += w6 * (k11 + 2.0f * (k21 + k31) + k41);
        y2 += w6 * (k12 + 2.0f * (k22 + k32) + k42);
        float* o = out + (size_t)(s + 1) * (size_t)B * 3 + (size_t)b * 3;
        o[0] = y0; o[1] = y1; o[2] = y2;
    }
}

extern "C" void kernel_launch(void* const* d_in, const int* in_sizes, int n_in,
                              void* d_out, int out_size, void* d_ws, size_t ws_size,
                              hipStream_t stream) {
    const float* sa  = (const float*)d_in[0];
    const float* T   = (const float*)d_in[1];
    const float* pW1 = (const float*)d_in[2];
    const float* pb1 = (const float*)d_in[3];
    const float* pW2 = (const float*)d_in[4];
    const float* pb2 = (const float*)d_in[5];
    const float* pW3 = (const float*)d_in[6];
    const float* pb3 = (const float*)d_in[7];
    const float* oW1 = (const float*)d_in[8];
    const float* ob1 = (const float*)d_in[9];
    const float* oW2 = (const float*)d_in[10];
    const float* ob2 = (const float*)d_in[11];
    float* out = (float*)d_out;

    const int B = in_sizes[0] / 6;            // 524288
    const int grid = (B + 255) / 256;         // 2048

    proj_kernel<<<grid, 256, 0, stream>>>(sa, pW1, pb1, pW2, pb2, pW3, pb3, out, B);
    ode_kernel<<<grid, 256, 0, stream>>>(T, oW1, ob1, oW2, ob2, out, B);
}